// Round 1
// baseline (2105.872 us; speedup 1.0000x reference)
//
#include <hip/hip_runtime.h>
#include <math.h>

#define L1_BINS 4096
#define L2_BINS 1024
#define L3_BINS 1024
#define MAX_SLOTS 32

// ---------------- device-global scratch (zeroed each launch) ----------------
__device__ unsigned int g_hist1[L1_BINS];
__device__ int          g_active1[L1_BINS];
__device__ unsigned int g_hist2[MAX_SLOTS * L2_BINS];
__device__ int          g_active2[MAX_SLOTS * L2_BINS];
__device__ unsigned int g_hist3[MAX_SLOTS * L3_BINS];

__device__ unsigned int g_bin1[32], g_res1[32];
__device__ int          g_slot1[32];
__device__ unsigned int g_bin2[32], g_res2[32];
__device__ int          g_slot2[32];
__device__ float        g_mn[16], g_mx[16];
__device__ unsigned int g_tkey[16];

// monotone float->uint key (order-preserving, equal floats -> equal keys)
__device__ __forceinline__ unsigned int f2key(float f) {
    unsigned int b = __float_as_uint(f);
    return (b & 0x80000000u) ? ~b : (b | 0x80000000u);
}
__device__ __forceinline__ float key2f(unsigned int k) {
    unsigned int b = (k & 0x80000000u) ? (k & 0x7FFFFFFFu) : ~k;
    return __uint_as_float(b);
}

// ---------------- kernels ----------------
__global__ void zero_scratch() {
    int i = blockIdx.x * blockDim.x + threadIdx.x;
    int stride = gridDim.x * blockDim.x;
    for (int j = i; j < L1_BINS; j += stride) { g_hist1[j] = 0u; g_active1[j] = 0; }
    for (int j = i; j < MAX_SLOTS * L2_BINS; j += stride) {
        g_hist2[j] = 0u; g_active2[j] = 0; g_hist3[j] = 0u;
    }
}

__global__ void hist1_kernel(const float4* __restrict__ x, int n4) {
    __shared__ unsigned int h[L1_BINS];
    for (int j = threadIdx.x; j < L1_BINS; j += blockDim.x) h[j] = 0u;
    __syncthreads();
    int stride = gridDim.x * blockDim.x;
    for (int i = blockIdx.x * blockDim.x + threadIdx.x; i < n4; i += stride) {
        float4 v = x[i];
        atomicAdd(&h[f2key(v.x) >> 20], 1u);
        atomicAdd(&h[f2key(v.y) >> 20], 1u);
        atomicAdd(&h[f2key(v.z) >> 20], 1u);
        atomicAdd(&h[f2key(v.w) >> 20], 1u);
    }
    __syncthreads();
    for (int j = threadIdx.x; j < L1_BINS; j += blockDim.x)
        if (h[j]) atomicAdd(&g_hist1[j], h[j]);
}

__global__ void select1_kernel(unsigned int n) {
    if (threadIdx.x != 0 || blockIdx.x != 0) return;
    unsigned int M = n >> 4;
    unsigned int ranks[32];
    for (int c = 0; c < 16; ++c) {
        ranks[2 * c]     = (unsigned int)c * M;            // chunk min rank
        ranks[2 * c + 1] = (unsigned int)(c + 1) * M - 1u; // chunk max rank
    }
    unsigned int cum = 0; int ri = 0;
    for (int b = 0; b < L1_BINS && ri < 32; ++b) {
        unsigned int c0 = cum; cum += g_hist1[b];
        while (ri < 32 && ranks[ri] < cum) {
            g_bin1[ri] = (unsigned int)b;
            g_res1[ri] = ranks[ri] - c0;
            ++ri;
        }
    }
    int nslot = 0;
    for (int i = 0; i < 32; ++i) {
        unsigned int b = g_bin1[i];
        if (g_active1[b] == 0) g_active1[b] = ++nslot;
        g_slot1[i] = g_active1[b] - 1;
    }
}

__global__ void hist2_kernel(const float4* __restrict__ x, int n4) {
    int stride = gridDim.x * blockDim.x;
    for (int i = blockIdx.x * blockDim.x + threadIdx.x; i < n4; i += stride) {
        float4 v = x[i];
        float vv[4] = {v.x, v.y, v.z, v.w};
#pragma unroll
        for (int k = 0; k < 4; ++k) {
            unsigned int key = f2key(vv[k]);
            int a = g_active1[key >> 20];
            if (a) atomicAdd(&g_hist2[(a - 1) * L2_BINS + ((key >> 10) & (L2_BINS - 1))], 1u);
        }
    }
}

__global__ void select2_kernel() {
    int i = threadIdx.x;
    if (i < 32) {
        int s = g_slot1[i];
        unsigned int r = g_res1[i];
        unsigned int cum = 0;
        for (int b = 0; b < L2_BINS; ++b) {
            unsigned int c0 = cum; cum += g_hist2[s * L2_BINS + b];
            if (r < cum) { g_bin2[i] = (unsigned int)b; g_res2[i] = r - c0; break; }
        }
    }
    __syncthreads();
    if (threadIdx.x == 0) {
        int nslot = 0;
        for (int j = 0; j < 32; ++j) {
            int idx = g_slot1[j] * L2_BINS + (int)g_bin2[j];
            if (g_active2[idx] == 0) g_active2[idx] = ++nslot;
            g_slot2[j] = g_active2[idx] - 1;
        }
    }
}

__global__ void hist3_kernel(const float4* __restrict__ x, int n4) {
    int stride = gridDim.x * blockDim.x;
    for (int i = blockIdx.x * blockDim.x + threadIdx.x; i < n4; i += stride) {
        float4 v = x[i];
        float vv[4] = {v.x, v.y, v.z, v.w};
#pragma unroll
        for (int k = 0; k < 4; ++k) {
            unsigned int key = f2key(vv[k]);
            int a = g_active1[key >> 20];
            if (a) {
                int a2 = g_active2[(a - 1) * L2_BINS + ((key >> 10) & (L2_BINS - 1))];
                if (a2) atomicAdd(&g_hist3[(a2 - 1) * L3_BINS + (key & (L3_BINS - 1))], 1u);
            }
        }
    }
}

__global__ void select3_kernel() {
    __shared__ unsigned int keys[32];
    int i = threadIdx.x;
    if (i < 32) {
        int s = g_slot2[i];
        unsigned int r = g_res2[i];
        unsigned int cum = 0, b3 = 0;
        for (int b = 0; b < L3_BINS; ++b) {
            cum += g_hist3[s * L3_BINS + b];
            if (r < cum) { b3 = (unsigned int)b; break; }
        }
        keys[i] = (g_bin1[i] << 20) | (g_bin2[i] << 10) | b3;
    }
    __syncthreads();
    if (threadIdx.x == 0) {
        for (int c = 0; c < 16; ++c) {
            g_mn[c]   = key2f(keys[2 * c]);
            g_mx[c]   = key2f(keys[2 * c + 1]);
            g_tkey[c] = keys[2 * c];
        }
        g_tkey[0] = 0u;  // sentinel: chunk 0 lower bound
    }
}

__global__ void quant_kernel(const float4* __restrict__ x, float4* __restrict__ out, int n4) {
    __shared__ float s_mn[16], s_mx[16];
    __shared__ unsigned int s_t[16];
    if (threadIdx.x < 16) {
        s_mn[threadIdx.x] = g_mn[threadIdx.x];
        s_mx[threadIdx.x] = g_mx[threadIdx.x];
        s_t[threadIdx.x]  = g_tkey[threadIdx.x];
    }
    __syncthreads();
    int stride = gridDim.x * blockDim.x;
    for (int i = blockIdx.x * blockDim.x + threadIdx.x; i < n4; i += stride) {
        float4 v = x[i];
        float r[4] = {v.x, v.y, v.z, v.w};
#pragma unroll
        for (int k = 0; k < 4; ++k) {
            float xv = r[k];
            unsigned int key = f2key(xv);
            // binary search: c = max{c in 0..15 : key >= t[c]}, t[0] = 0
            int c = (key >= s_t[8]) ? 8 : 0;
            if (key >= s_t[c + 4]) c += 4;
            if (key >= s_t[c + 2]) c += 2;
            if (key >= s_t[c + 1]) c += 1;
            float mn = s_mn[c], mx = s_mx[c];
            float outv;
            if (mn == mx) {
                outv = xv;  // passthrough chunk
            } else {
                float st = (mx - mn) / 15.0f;          // matches ref: (mx-mn)/levels
                if (st == 0.0f) st = 1.0f;             // safe_step
                float q = rintf((xv - mn) / st);       // round-half-even like jnp.round
                outv = __fadd_rn(__fmul_rn(q, st), mn); // no fma contraction: mul then add
            }
            r[k] = outv;
        }
        out[i] = make_float4(r[0], r[1], r[2], r[3]);
    }
}

// ---------------- launch ----------------
extern "C" void kernel_launch(void* const* d_in, const int* in_sizes, int n_in,
                              void* d_out, int out_size, void* d_ws, size_t ws_size,
                              hipStream_t stream) {
    const float* x = (const float*)d_in[0];
    float* out = (float*)d_out;
    int n  = in_sizes[0];
    int n4 = n / 4;

    zero_scratch<<<256, 256, 0, stream>>>();
    hist1_kernel<<<2048, 256, 0, stream>>>((const float4*)x, n4);
    select1_kernel<<<1, 64, 0, stream>>>((unsigned int)n);
    hist2_kernel<<<2048, 256, 0, stream>>>((const float4*)x, n4);
    select2_kernel<<<1, 64, 0, stream>>>();
    hist3_kernel<<<2048, 256, 0, stream>>>((const float4*)x, n4);
    select3_kernel<<<1, 64, 0, stream>>>();
    quant_kernel<<<4096, 256, 0, stream>>>((const float4*)x, (float4*)out, n4);
}

// Round 2
// 742.201 us; speedup vs baseline: 2.8373x; 2.8373x over previous
//
#include <hip/hip_runtime.h>
#include <math.h>

#define L1B 4096        // 12-bit level 1
#define L2B 512         // 9-bit level 2
#define L3B 2048        // 11-bit level 3
#define SLOTS 32
#define H1_BLOCKS 512
#define H2_BLOCKS 256
#define H2_WORDS (SLOTS * L2B / 2)   // 8192 u32 words (packed u16 counters)

// ---------------- device-global scratch ----------------
__device__ unsigned int g_part1[H1_BLOCKS * L1B];      // 8 MB, fully overwritten
__device__ unsigned int g_part2[H2_BLOCKS * H2_WORDS]; // 8 MB, fully overwritten
__device__ unsigned int g_hist1[L1B];                  // overwritten by reduce1
__device__ unsigned int g_hist2[SLOTS * L2B];          // overwritten by reduce2
__device__ unsigned int g_hist3[SLOTS * L3B];          // zeroed each launch
__device__ unsigned char g_sid1[L1B];                  // slot+1 per level-1 bin, zeroed
__device__ unsigned char g_sid2[SLOTS * L2B];          // slot+1 per (slot1,bin2), zeroed

__device__ unsigned int g_bin1[32], g_res1[32];
__device__ int          g_slot1[32];
__device__ unsigned int g_bin2[32], g_res2[32];
__device__ int          g_slot2[32];
__device__ unsigned int g_bin3[32], g_res3[32];
__device__ float        g_mn[16], g_mx[16];
__device__ unsigned int g_tkey[16];

// monotone float->uint key
__device__ __forceinline__ unsigned int f2key(float f) {
    unsigned int b = __float_as_uint(f);
    return (b & 0x80000000u) ? ~b : (b | 0x80000000u);
}
__device__ __forceinline__ float key2f(unsigned int k) {
    unsigned int b = (k & 0x80000000u) ? (k & 0x7FFFFFFFu) : ~k;
    return __uint_as_float(b);
}

// ---------------- zero ----------------
__global__ void zero_scratch() {
    int i = blockIdx.x * blockDim.x + threadIdx.x;
    int stride = gridDim.x * blockDim.x;
    for (int j = i; j < SLOTS * L3B; j += stride) g_hist3[j] = 0u;
    unsigned int* s1 = (unsigned int*)g_sid1;
    for (int j = i; j < L1B / 4; j += stride) s1[j] = 0u;
    unsigned int* s2 = (unsigned int*)g_sid2;
    for (int j = i; j < SLOTS * L2B / 4; j += stride) s2[j] = 0u;
}

// ---------------- level 1 histogram ----------------
__global__ void hist1_kernel(const float4* __restrict__ x, int n4) {
    __shared__ unsigned int h[2 * L1B];  // 32 KB, 2 sub-hists by wave parity
    for (int j = threadIdx.x; j < 2 * L1B; j += blockDim.x) h[j] = 0u;
    __syncthreads();
    unsigned int* hp = &h[((threadIdx.x >> 6) & 1) * L1B];
    int stride = gridDim.x * blockDim.x;
    for (int i = blockIdx.x * blockDim.x + threadIdx.x; i < n4; i += stride) {
        float4 v = x[i];
        atomicAdd(&hp[f2key(v.x) >> 20], 1u);
        atomicAdd(&hp[f2key(v.y) >> 20], 1u);
        atomicAdd(&hp[f2key(v.z) >> 20], 1u);
        atomicAdd(&hp[f2key(v.w) >> 20], 1u);
    }
    __syncthreads();
    for (int j = threadIdx.x; j < L1B; j += blockDim.x)
        g_part1[blockIdx.x * L1B + j] = h[j] + h[L1B + j];
}

__global__ void reduce1_kernel() {
    int j = blockIdx.x * blockDim.x + threadIdx.x;  // 4096 threads
    if (j >= L1B) return;
    unsigned int s = 0;
    for (int b = 0; b < H1_BLOCKS; ++b) s += g_part1[b * L1B + j];
    g_hist1[j] = s;
}

// ---------------- wave-parallel rank select ----------------
// One 64-lane wave: find bin with prefix <= r < prefix+hist[bin]; nbins % 64 == 0.
__device__ void wave_select(const unsigned int* __restrict__ hist, int nbins,
                            unsigned int r, unsigned int* out_bin, unsigned int* out_res) {
    int lane = threadIdx.x & 63;
    unsigned int base = 0;
    for (int k = 0; k < nbins; k += 64) {
        unsigned int v = hist[k + lane];
        unsigned int incl = v;
#pragma unroll
        for (int off = 1; off < 64; off <<= 1) {
            unsigned int t = (unsigned int)__shfl_up((int)incl, off, 64);
            if (lane >= off) incl += t;
        }
        unsigned int total = (unsigned int)__shfl((int)incl, 63, 64);
        if (r < base + total) {  // uniform branch
            unsigned long long m = __ballot(base + incl > r);
            int fl = __ffsll((long long)m) - 1;
            unsigned int incl_fl = (unsigned int)__shfl((int)incl, fl, 64);
            unsigned int v_fl = (unsigned int)__shfl((int)v, fl, 64);
            if (lane == 0) {
                *out_bin = (unsigned int)(k + fl);
                *out_res = r - (base + incl_fl - v_fl);
            }
            return;
        }
        base += total;
    }
}

__global__ void select1_kernel(unsigned int n) {
    int i = blockIdx.x;  // 32 blocks x 64 threads
    unsigned int M = n >> 4;
    unsigned int c = (unsigned int)(i >> 1);
    unsigned int r = (i & 1) ? ((c + 1) * M - 1u) : (c * M);
    wave_select(g_hist1, L1B, r, &g_bin1[i], &g_res1[i]);
}

__global__ void assign1_kernel() {
    if (threadIdx.x != 0 || blockIdx.x != 0) return;
    int nslot = 0;
    for (int i = 0; i < 32; ++i) {
        unsigned int b = g_bin1[i];
        if (g_sid1[b] == 0) g_sid1[b] = (unsigned char)(++nslot);
        g_slot1[i] = g_sid1[b] - 1;
    }
}

// ---------------- level 2 histogram (LDS packed u16, partial dump) ----------------
__global__ void hist2_kernel(const float4* __restrict__ x, int n4) {
    __shared__ unsigned int h2[H2_WORDS];      // 32 KB
    __shared__ unsigned char sid1[L1B];        // 4 KB
    for (int j = threadIdx.x; j < H2_WORDS; j += blockDim.x) h2[j] = 0u;
    unsigned int* s1w = (unsigned int*)sid1;
    for (int j = threadIdx.x; j < L1B / 4; j += blockDim.x) s1w[j] = ((const unsigned int*)g_sid1)[j];
    __syncthreads();
    int stride = gridDim.x * blockDim.x;
    for (int i = blockIdx.x * blockDim.x + threadIdx.x; i < n4; i += stride) {
        float4 v = x[i];
        float vv[4] = {v.x, v.y, v.z, v.w};
#pragma unroll
        for (int k = 0; k < 4; ++k) {
            unsigned int key = f2key(vv[k]);
            unsigned int s = sid1[key >> 20];
            if (s) {
                unsigned int c = ((s - 1) << 9) | ((key >> 11) & (L2B - 1));
                atomicAdd(&h2[c >> 1], 1u << ((c & 1) << 4));
            }
        }
    }
    __syncthreads();
    for (int j = threadIdx.x; j < H2_WORDS; j += blockDim.x)
        g_part2[blockIdx.x * H2_WORDS + j] = h2[j];
}

__global__ void reduce2_kernel() {
    int w = blockIdx.x * blockDim.x + threadIdx.x;  // 8192 threads
    if (w >= H2_WORDS) return;
    unsigned int lo = 0, hi = 0;
    for (int b = 0; b < H2_BLOCKS; ++b) {
        unsigned int u = g_part2[b * H2_WORDS + w];
        lo += u & 0xFFFFu;
        hi += u >> 16;
    }
    g_hist2[2 * w] = lo;
    g_hist2[2 * w + 1] = hi;
}

__global__ void select2_kernel() {
    int i = blockIdx.x;  // 32 blocks x 64 threads
    int s = g_slot1[i];
    wave_select(g_hist2 + s * L2B, L2B, g_res1[i], &g_bin2[i], &g_res2[i]);
}

__global__ void assign2_kernel() {
    if (threadIdx.x != 0 || blockIdx.x != 0) return;
    int nslot = 0;
    for (int i = 0; i < 32; ++i) {
        int p = g_slot1[i] * L2B + (int)g_bin2[i];
        if (g_sid2[p] == 0) g_sid2[p] = (unsigned char)(++nslot);
        g_slot2[i] = g_sid2[p] - 1;
    }
}

// ---------------- level 3 histogram (sparse -> global atomics OK) ----------------
__global__ void hist3_kernel(const float4* __restrict__ x, int n4) {
    __shared__ unsigned char sid1[L1B];          // 4 KB
    __shared__ unsigned char sid2[SLOTS * L2B];  // 16 KB
    unsigned int* s1w = (unsigned int*)sid1;
    for (int j = threadIdx.x; j < L1B / 4; j += blockDim.x) s1w[j] = ((const unsigned int*)g_sid1)[j];
    unsigned int* s2w = (unsigned int*)sid2;
    for (int j = threadIdx.x; j < SLOTS * L2B / 4; j += blockDim.x) s2w[j] = ((const unsigned int*)g_sid2)[j];
    __syncthreads();
    int stride = gridDim.x * blockDim.x;
    for (int i = blockIdx.x * blockDim.x + threadIdx.x; i < n4; i += stride) {
        float4 v = x[i];
        float vv[4] = {v.x, v.y, v.z, v.w};
#pragma unroll
        for (int k = 0; k < 4; ++k) {
            unsigned int key = f2key(vv[k]);
            unsigned int s = sid1[key >> 20];
            if (s) {
                unsigned int s2 = sid2[((s - 1) << 9) | ((key >> 11) & (L2B - 1))];
                if (s2) atomicAdd(&g_hist3[((s2 - 1) << 11) | (key & (L3B - 1))], 1u);
            }
        }
    }
}

__global__ void select3_kernel() {
    int i = blockIdx.x;  // 32 blocks x 64 threads
    int s2 = g_slot2[i];
    wave_select(g_hist3 + s2 * L3B, L3B, g_res2[i], &g_bin3[i], &g_res3[i]);
}

__global__ void finalize_kernel() {
    int c = threadIdx.x;  // 32 threads; use first 16
    if (c < 16) {
        unsigned int klo = (g_bin1[2 * c] << 20) | (g_bin2[2 * c] << 11) | g_bin3[2 * c];
        unsigned int khi = (g_bin1[2 * c + 1] << 20) | (g_bin2[2 * c + 1] << 11) | g_bin3[2 * c + 1];
        g_mn[c] = key2f(klo);
        g_mx[c] = key2f(khi);
        g_tkey[c] = (c == 0) ? 0u : klo;  // sentinel lower bound for chunk 0
    }
}

// ---------------- final quantization ----------------
__global__ void quant_kernel(const float4* __restrict__ x, float4* __restrict__ out, int n4) {
    __shared__ float s_mn[16], s_mx[16];
    __shared__ unsigned int s_t[16];
    if (threadIdx.x < 16) {
        s_mn[threadIdx.x] = g_mn[threadIdx.x];
        s_mx[threadIdx.x] = g_mx[threadIdx.x];
        s_t[threadIdx.x]  = g_tkey[threadIdx.x];
    }
    __syncthreads();
    int stride = gridDim.x * blockDim.x;
    for (int i = blockIdx.x * blockDim.x + threadIdx.x; i < n4; i += stride) {
        float4 v = x[i];
        float r[4] = {v.x, v.y, v.z, v.w};
#pragma unroll
        for (int k = 0; k < 4; ++k) {
            float xv = r[k];
            unsigned int key = f2key(xv);
            int c = (key >= s_t[8]) ? 8 : 0;
            if (key >= s_t[c + 4]) c += 4;
            if (key >= s_t[c + 2]) c += 2;
            if (key >= s_t[c + 1]) c += 1;
            float mn = s_mn[c], mx = s_mx[c];
            float outv;
            if (mn == mx) {
                outv = xv;
            } else {
                float st = (mx - mn) / 15.0f;
                if (st == 0.0f) st = 1.0f;
                float q = rintf((xv - mn) / st);
                outv = __fadd_rn(__fmul_rn(q, st), mn);  // match np: mul then add, no fma
            }
            r[k] = outv;
        }
        out[i] = make_float4(r[0], r[1], r[2], r[3]);
    }
}

// ---------------- launch ----------------
extern "C" void kernel_launch(void* const* d_in, const int* in_sizes, int n_in,
                              void* d_out, int out_size, void* d_ws, size_t ws_size,
                              hipStream_t stream) {
    const float* x = (const float*)d_in[0];
    float* out = (float*)d_out;
    int n  = in_sizes[0];
    int n4 = n / 4;

    zero_scratch<<<128, 256, 0, stream>>>();
    hist1_kernel<<<H1_BLOCKS, 512, 0, stream>>>((const float4*)x, n4);
    reduce1_kernel<<<16, 256, 0, stream>>>();
    select1_kernel<<<32, 64, 0, stream>>>((unsigned int)n);
    assign1_kernel<<<1, 64, 0, stream>>>();
    hist2_kernel<<<H2_BLOCKS, 512, 0, stream>>>((const float4*)x, n4);
    reduce2_kernel<<<32, 256, 0, stream>>>();
    select2_kernel<<<32, 64, 0, stream>>>();
    assign2_kernel<<<1, 64, 0, stream>>>();
    hist3_kernel<<<2048, 256, 0, stream>>>((const float4*)x, n4);
    select3_kernel<<<32, 64, 0, stream>>>();
    finalize_kernel<<<1, 64, 0, stream>>>();
    quant_kernel<<<4096, 256, 0, stream>>>((const float4*)x, (float4*)out, n4);
}